// Round 1
// baseline (567.075 us; speedup 1.0000x reference)
//
#include <hip/hip_runtime.h>
#include <hip/hip_bf16.h>

#define B_ 16
#define S_ 4096
#define E_ 768
#define H_ 4
#define A_ 128

constexpr float ALPHA = 0.2f;

typedef __attribute__((ext_vector_type(4))) float f32x4;
typedef __attribute__((ext_vector_type(8))) short bf16x8;

__device__ __forceinline__ unsigned short f2bf(float f) {
    union { float f; unsigned int u; } v;
    v.f = f;
    unsigned int u = v.u;
    unsigned int r = (u + 0x7FFFu + ((u >> 16) & 1u)) >> 16;
    return (unsigned short)r;
}

// ---------------------------------------------------------------------------
// Kernel 1: transpose + bf16-convert weights.
// W1T[h][a][e] = bf16(W1[h][e][a]);  W2T[h][e][a] = bf16(W2[h][a][e])
// ---------------------------------------------------------------------------
__global__ void k_prep(const float* __restrict__ w1, const float* __restrict__ w2,
                       unsigned short* __restrict__ w1t, unsigned short* __restrict__ w2t) {
    int idx = blockIdx.x * 256 + threadIdx.x;
    const int n = H_ * A_ * E_;  // 393216
    if (idx >= n) return;
    // w1t[h][a][e]
    {
        int e = idx % E_; int ha = idx / E_;
        int a = ha % A_;  int h  = ha / A_;
        w1t[idx] = f2bf(w1[(h * E_ + e) * A_ + a]);
    }
    // w2t[h][e][a]
    {
        int a = idx % A_; int he = idx / A_;
        int e = he % E_;  int h  = he / E_;
        w2t[idx] = f2bf(w2[(h * A_ + a) * E_ + e]);
    }
}

// ---------------------------------------------------------------------------
// Kernel 2: Hm[b,h,s,a] = bf16( leakyrelu( x[b,s,:] @ W1[h,:,a] + b1[h,a] ) )
// block: 256 thr (4 waves). tile 128s x 128a, K=768 in BK=64 chunks.
// grid: x = st*4 + h  (128), y = b (16)
// ---------------------------------------------------------------------------
__global__ __launch_bounds__(256) void k_stage1(
    const float* __restrict__ x, const unsigned short* __restrict__ w1t,
    const float* __restrict__ b1, unsigned short* __restrict__ hm) {

    const int bx = blockIdx.x;
    const int h  = bx & 3;
    const int st = bx >> 2;          // 0..31
    const int b  = blockIdx.y;
    const int tid  = threadIdx.x;
    const int wave = tid >> 6;
    const int lane = tid & 63;
    const int lr = lane & 15;        // fragment row/col index
    const int lg = lane >> 4;        // k-group

    __shared__ unsigned short ldsb[128 * 64];  // W1T tile [a=128][e=64], swizzled, 16KB

    const int s0 = st * 128;
    f32x4 acc[2][8];
#pragma unroll
    for (int i = 0; i < 2; ++i)
#pragma unroll
        for (int j = 0; j < 8; ++j) acc[i][j] = (f32x4)0.0f;

    const float* xb = x + ((size_t)b * S_ + s0 + wave * 32) * E_;
    const unsigned short* w1h = w1t + (size_t)h * A_ * E_;

    for (int e0 = 0; e0 < E_; e0 += 64) {
        __syncthreads();
        // stage W1T tile: 128 rows x 128B = 1024 x 16B slots
#pragma unroll
        for (int it = 0; it < 4; ++it) {
            int slot = tid + it * 256;
            int row  = slot >> 3;
            int c16  = slot & 7;
            bf16x8 v = *(const bf16x8*)(w1h + row * E_ + e0 + c16 * 8);
            int byte = (row * 128 + c16 * 16) ^ ((row & 7) << 4);
            *(bf16x8*)((char*)ldsb + byte) = v;
        }
        __syncthreads();
#pragma unroll
        for (int g2 = 0; g2 < 2; ++g2) {
            bf16x8 afr[2];
#pragma unroll
            for (int sf = 0; sf < 2; ++sf) {
                const float* p = xb + (sf * 16 + lr) * E_ + e0 + g2 * 32 + lg * 8;
                f32x4 v0 = *(const f32x4*)p;
                f32x4 v1 = *(const f32x4*)(p + 4);
                bf16x8 a;
#pragma unroll
                for (int j = 0; j < 4; ++j) {
                    a[j]     = (short)f2bf(v0[j]);
                    a[4 + j] = (short)f2bf(v1[j]);
                }
                afr[sf] = a;
            }
#pragma unroll
            for (int nf = 0; nf < 8; ++nf) {
                int row  = nf * 16 + lr;
                int byte = (row * 128 + g2 * 64 + lg * 16) ^ ((row & 7) << 4);
                bf16x8 bfr = *(const bf16x8*)((char*)ldsb + byte);
                acc[0][nf] = __builtin_amdgcn_mfma_f32_16x16x32_bf16(afr[0], bfr, acc[0][nf], 0, 0, 0);
                acc[1][nf] = __builtin_amdgcn_mfma_f32_16x16x32_bf16(afr[1], bfr, acc[1][nf], 0, 0, 0);
            }
        }
    }

    // epilogue: + b1, leakyrelu, bf16 store.  C layout: col = lr, row = lg*4 + j
    const size_t hmbase = ((size_t)(b * H_ + h) * S_ + s0 + wave * 32) * A_;
#pragma unroll
    for (int nf = 0; nf < 8; ++nf) {
        float bias = b1[h * A_ + nf * 16 + lr];
#pragma unroll
        for (int sf = 0; sf < 2; ++sf) {
#pragma unroll
            for (int j = 0; j < 4; ++j) {
                float v = acc[sf][nf][j] + bias;
                v = v >= 0.0f ? v : ALPHA * v;
                hm[hmbase + (size_t)(sf * 16 + lg * 4 + j) * A_ + nf * 16 + lr] = f2bf(v);
            }
        }
    }
}

// ---------------------------------------------------------------------------
// Kernel 3: fused logits + online softmax-partials + weighted x accumulation.
// block: (e-tile of 128, h, b, s-quarter). 4 waves, each wave strides 16-row
// chunks. Writes per-block partial (m, Z, O)[128 cols] to ws.
// grid: x = et*4 + h (24), y = b (16), z = sc (4)
// ---------------------------------------------------------------------------
__global__ __launch_bounds__(256) void k_stage2(
    const float* __restrict__ x, const unsigned short* __restrict__ hm,
    const unsigned short* __restrict__ w2t, const float* __restrict__ b2,
    float* __restrict__ part) {

    const int bx = blockIdx.x;
    const int h  = bx & 3;
    const int et = bx >> 2;          // 0..5
    const int b  = blockIdx.y;
    const int scq = blockIdx.z;      // s-quarter 0..3
    const int tid  = threadIdx.x;
    const int wave = tid >> 6;
    const int lane = tid & 63;
    const int lr = lane & 15;
    const int lg = lane >> 4;
    const int e0 = et * 128;

    __shared__ unsigned short ldsw[128 * 128];  // W2T tile [e=128][a=128] swizzled, 32KB
    __shared__ float ldsm[4][128][3];           // per-wave (m,Z,O), 6KB

    // load W2T tile once: 128 rows x 256B = 2048 x 16B slots
#pragma unroll
    for (int it = 0; it < 8; ++it) {
        int slot = tid + it * 256;
        int row  = slot >> 4;
        int c16  = slot & 15;
        bf16x8 v = *(const bf16x8*)(w2t + ((size_t)h * E_ + e0 + row) * A_ + c16 * 8);
        int byte = (row * 256 + c16 * 16) ^ ((row & 7) << 4);
        *(bf16x8*)((char*)ldsw + byte) = v;
    }
    __syncthreads();

    float m[8], z[8], o[8], bias[8];
#pragma unroll
    for (int nf = 0; nf < 8; ++nf) {
        m[nf] = -INFINITY; z[nf] = 0.0f; o[nf] = 0.0f;
        bias[nf] = b2[h * E_ + e0 + nf * 16 + lr];
    }

    const unsigned short* hmb = hm + (size_t)(b * H_ + h) * S_ * A_;
    const float* xb = x + (size_t)b * S_ * E_;
    const int send = (scq + 1) * (S_ / 4);

    for (int s = scq * (S_ / 4) + wave * 16; s < send; s += 64) {
        f32x4 lac[8];
#pragma unroll
        for (int nf = 0; nf < 8; ++nf) lac[nf] = (f32x4)0.0f;
#pragma unroll
        for (int ks = 0; ks < 4; ++ks) {
            bf16x8 af = *(const bf16x8*)(hmb + (size_t)(s + lr) * A_ + ks * 32 + lg * 8);
#pragma unroll
            for (int nf = 0; nf < 8; ++nf) {
                int row  = nf * 16 + lr;
                int byte = (row * 256 + ks * 64 + lg * 16) ^ ((row & 7) << 4);
                bf16x8 bfr = *(const bf16x8*)((char*)ldsw + byte);
                lac[nf] = __builtin_amdgcn_mfma_f32_16x16x32_bf16(af, bfr, lac[nf], 0, 0, 0);
            }
        }
        // online softmax update. lac[nf][j] = logit(row = s + lg*4 + j, col = e0+nf*16+lr) - bias
#pragma unroll
        for (int nf = 0; nf < 8; ++nf) {
            float l0 = lac[nf][0] + bias[nf];
            float l1 = lac[nf][1] + bias[nf];
            float l2 = lac[nf][2] + bias[nf];
            float l3 = lac[nf][3] + bias[nf];
            float cm = fmaxf(fmaxf(l0, l1), fmaxf(l2, l3));
            cm = fmaxf(cm, __shfl_xor(cm, 16));
            cm = fmaxf(cm, __shfl_xor(cm, 32));
            float mn = fmaxf(m[nf], cm);
            float sca = __expf(m[nf] - mn);
            z[nf] *= sca; o[nf] *= sca; m[nf] = mn;
            float p0 = __expf(l0 - mn);
            float p1 = __expf(l1 - mn);
            float p2 = __expf(l2 - mn);
            float p3 = __expf(l3 - mn);
            z[nf] += (p0 + p1) + (p2 + p3);
            const float* xp = xb + (size_t)(s + lg * 4) * E_ + e0 + nf * 16 + lr;
            o[nf] += p0 * xp[0];
            o[nf] += p1 * xp[E_];
            o[nf] += p2 * xp[2 * E_];
            o[nf] += p3 * xp[3 * E_];
        }
    }

    // wave-level butterfly: combine the 4 row-groups (m is already uniform)
#pragma unroll
    for (int nf = 0; nf < 8; ++nf) {
        z[nf] += __shfl_xor(z[nf], 16); z[nf] += __shfl_xor(z[nf], 32);
        o[nf] += __shfl_xor(o[nf], 16); o[nf] += __shfl_xor(o[nf], 32);
    }
    if (lane < 16) {
#pragma unroll
        for (int nf = 0; nf < 8; ++nf) {
            ldsm[wave][nf * 16 + lane][0] = m[nf];
            ldsm[wave][nf * 16 + lane][1] = z[nf];
            ldsm[wave][nf * 16 + lane][2] = o[nf];
        }
    }
    __syncthreads();
    // merge 4 waves, write block partial
    if (tid < 128) {
        float M = -INFINITY;
#pragma unroll
        for (int w = 0; w < 4; ++w) M = fmaxf(M, ldsm[w][tid][0]);
        float Z = 0.0f, O = 0.0f;
#pragma unroll
        for (int w = 0; w < 4; ++w) {
            float sca = __expf(ldsm[w][tid][0] - M);
            Z += ldsm[w][tid][1] * sca;
            O += ldsm[w][tid][2] * sca;
        }
        size_t base = (size_t)(((b * H_ + h) * 6 + et) * 4 + scq) * 128 * 3;
        part[base + tid * 3 + 0] = M;
        part[base + tid * 3 + 1] = Z;
        part[base + tid * 3 + 2] = O;
    }
}

// ---------------------------------------------------------------------------
// Kernel 4: merge the 4 s-quarter partials, out = O/Z.  out[b,h,e]
// ---------------------------------------------------------------------------
__global__ void k_merge(const float* __restrict__ part, float* __restrict__ out) {
    int idx = blockIdx.x * 256 + threadIdx.x;
    if (idx >= B_ * H_ * E_) return;
    int e  = idx % E_;
    int bh = idx / E_;
    int et = e >> 7;
    int c  = e & 127;
    float M = -INFINITY;
#pragma unroll
    for (int q = 0; q < 4; ++q) {
        const float* p = part + ((size_t)((bh * 6 + et) * 4 + q) * 128 + c) * 3;
        M = fmaxf(M, p[0]);
    }
    float Z = 0.0f, O = 0.0f;
#pragma unroll
    for (int q = 0; q < 4; ++q) {
        const float* p = part + ((size_t)((bh * 6 + et) * 4 + q) * 128 + c) * 3;
        float sca = __expf(p[0] - M);
        Z += p[1] * sca;
        O += p[2] * sca;
    }
    out[idx] = O / Z;
}

// ---------------------------------------------------------------------------
extern "C" void kernel_launch(void* const* d_in, const int* in_sizes, int n_in,
                              void* d_out, int out_size, void* d_ws, size_t ws_size,
                              hipStream_t stream) {
    const float* x  = (const float*)d_in[0];
    const float* w1 = (const float*)d_in[1];
    const float* b1 = (const float*)d_in[2];
    const float* w2 = (const float*)d_in[3];
    const float* b2 = (const float*)d_in[4];
    float* out = (float*)d_out;

    char* ws = (char*)d_ws;
    unsigned short* hm  = (unsigned short*)ws;                          // 64 MB
    unsigned short* w1t = (unsigned short*)(ws + 67108864);             // 768 KB
    unsigned short* w2t = (unsigned short*)(ws + 67108864 + 786432);    // 768 KB
    float*          prt = (float*)(ws + 67108864 + 2 * 786432);         // 2.25 MB

    k_prep<<<dim3(1536), 256, 0, stream>>>(w1, w2, w1t, w2t);
    k_stage1<<<dim3(128, 16), 256, 0, stream>>>(x, w1t, b1, hm);
    k_stage2<<<dim3(24, 16, 4), 256, 0, stream>>>(x, hm, w2t, b2, prt);
    k_merge<<<dim3(192), 256, 0, stream>>>(prt, out);
}